// Round 4
// baseline (698.033 us; speedup 1.0000x reference)
//
#include <hip/hip_runtime.h>

// TinyLSTM: I=128, H=64, C=10, B=256, T=1024
// R11: minimal-consumer design. Post-mortems R8-R10 establish: step time =
// serial chain (barrier -> ds_read h ~120 -> h-MFMA ~60 -> extract ~25 ->
// act ~140 -> write+drain ~50 -> barrier ~40 = 430-480 cyc) PLUS nearly 1:1
// whatever else the wave does (no co-issue at 1 wave/SIMD; every lgkm op
// also pushes the pre-barrier lgkmcnt(0) drain). R9 (306us) won by having
// the smallest consumer body; R10 regressed by folding work in. So R11
// makes the body SMALLER than R9's:
//  - kernel A (cast_x): x -> f16 workspace xh[b][t][k] once (bit-identical
//    to the in-kernel cvt_pkrtz this replaces).
//  - kernel B (lstm_rec): 64 blocks x 4 waves, NO producers. Per step the
//    4 x-B-frags come from a depth-4 static register ring fed by
//    global_load_dwordx4 issued 4 steps ahead (vm pipe: immune to the
//    lgkm-only barrier drain). The 16 x-MFMAs issue inside the hb-read
//    shadow (~96 cyc issue < ~160 cyc shadow). Consumer LDS ops: 3/step
//    (2 hb reads + 1 h write) vs R9's 7. No XS, no P, no gll, no vmcnt.
//    Accumulation order bias -> x-ksteps -> h-ksteps == R9 -> bit-identical.
//  - ws_size < 64MB fallback: template path loads f32 x (depth-2 ring,
//    in-step pack8n).

#define NI 128
#define NH 64
#define NB 256
#define NT 1024
#define NC 10

#define LOG2E    1.44269504f
#define TWOLOG2E 2.88539008f

typedef __fp16 half2v __attribute__((ext_vector_type(2)));
typedef __fp16 f16x8  __attribute__((ext_vector_type(8)));
typedef float  f32x4  __attribute__((ext_vector_type(4)));

#define HP 80            // H row stride (halves): 160 B, max 2-way banks

#define MF(acc, a, b) \
    acc = __builtin_amdgcn_mfma_f32_16x16x32_f16(a, b, acc, 0, 0, 0)

__device__ __forceinline__ void block_sync_lds() {
    asm volatile("s_waitcnt lgkmcnt(0)\n\ts_barrier" ::: "memory");
}
__device__ __forceinline__ float fast_exp2(float x) {
#if __has_builtin(__builtin_amdgcn_exp2f)
    return __builtin_amdgcn_exp2f(x);
#else
    return __exp2f(x);
#endif
}
__device__ __forceinline__ float fast_rcp(float x) {
    return __builtin_amdgcn_rcpf(x);
}
__device__ __forceinline__ f16x8 pack8(float4 a, float4 b, float s) {
    half2v p0 = __builtin_amdgcn_cvt_pkrtz(a.x * s, a.y * s);
    half2v p1 = __builtin_amdgcn_cvt_pkrtz(a.z * s, a.w * s);
    half2v p2 = __builtin_amdgcn_cvt_pkrtz(b.x * s, b.y * s);
    half2v p3 = __builtin_amdgcn_cvt_pkrtz(b.z * s, b.w * s);
    f16x8 r;
    r[0]=p0[0]; r[1]=p0[1]; r[2]=p1[0]; r[3]=p1[1];
    r[4]=p2[0]; r[5]=p2[1]; r[6]=p3[0]; r[7]=p3[1];
    return r;
}
__device__ __forceinline__ f16x8 pack8n(float4 a, float4 b) {
    half2v p0 = __builtin_amdgcn_cvt_pkrtz(a.x, a.y);
    half2v p1 = __builtin_amdgcn_cvt_pkrtz(a.z, a.w);
    half2v p2 = __builtin_amdgcn_cvt_pkrtz(b.x, b.y);
    half2v p3 = __builtin_amdgcn_cvt_pkrtz(b.z, b.w);
    f16x8 r;
    r[0]=p0[0]; r[1]=p0[1]; r[2]=p1[0]; r[3]=p1[1];
    r[4]=p2[0]; r[5]=p2[1]; r[6]=p3[0]; r[7]=p3[1];
    return r;
}

// ---- kernel A: x (f32) -> xh (f16), same cvt_pkrtz as the fused path ----
__global__ __launch_bounds__(256)
void cast_x(const float* __restrict__ x, __fp16* __restrict__ xh) {
    const int n8 = NB * NT * NI / 8;
    int i = blockIdx.x * blockDim.x + threadIdx.x;
    for (; i < n8; i += gridDim.x * blockDim.x) {
        float4 a = ((const float4*)x)[2 * i];
        float4 b = ((const float4*)x)[2 * i + 1];
        ((f16x8*)xh)[i] = pack8n(a, b);
    }
}

// ---- kernel B: the recurrence ----
template<int XF16>
__global__ __launch_bounds__(256, 1)
void lstm_rec(const float* __restrict__ x,
              const __fp16* __restrict__ xh,
              const float* __restrict__ W_ih,
              const float* __restrict__ W_hh,
              const float* __restrict__ b_ih,
              const float* __restrict__ b_hh,
              const float* __restrict__ W_cls,
              const float* __restrict__ b_cls,
              float* __restrict__ out) {
    const int tid  = threadIdx.x;
    const int w    = tid >> 6;     // wave: gate rows 64i+16w+col
    const int lane = tid & 63;
    const int col  = lane & 15;    // MFMA n-column
    const int quad = lane >> 4;
    const int bb   = blockIdx.x;   // batches [4bb, 4bb+4)
    const int bcol = col & 3;      // batch within group (cols replicate x4)
    const int cr   = col >> 2;     // the one C-row this lane activates

    __shared__ __align__(16) __fp16 H2[2][4][HP];   // h f16, dbl-buf, 1.3 KB

    // ---- weights as MFMA A-frags, prescaled bias ----
    f16x8 afrX[4][4];   // W_ih, K=128 (4 ksteps)
    f16x8 afrH[4][2];   // W_hh, K=64  (2 ksteps)
    f32x4 biasf[4];
    #pragma unroll
    for (int i = 0; i < 4; ++i) {
        const int grow = 64 * i + 16 * w + col;
        const float s = (i == 2) ? TWOLOG2E : LOG2E;
        const float* Wx = W_ih + (size_t)grow * NI;
        #pragma unroll
        for (int ks = 0; ks < 4; ++ks) {
            float4 a4 = *(const float4*)(Wx + ks * 32 + quad * 8);
            float4 b4 = *(const float4*)(Wx + ks * 32 + quad * 8 + 4);
            afrX[i][ks] = pack8(a4, b4, s);
        }
        const float* Wh = W_hh + (size_t)grow * NH;
        #pragma unroll
        for (int ks = 0; ks < 2; ++ks) {
            float4 a4 = *(const float4*)(Wh + ks * 32 + quad * 8);
            float4 b4 = *(const float4*)(Wh + ks * 32 + quad * 8 + 4);
            afrH[i][ks] = pack8(a4, b4, s);
        }
        #pragma unroll
        for (int r = 0; r < 4; ++r) {
            const int u = 64 * i + 16 * w + 4 * quad + r;
            biasf[i][r] = (b_ih[u] + b_hh[u]) * s;
        }
    }
    for (int z = tid; z < 2 * 4 * HP / 2; z += 256)
        ((unsigned*)H2)[z] = 0u;        // zero both H bufs

    // ---- per-lane x addressing: B-frag = halves [ks*32+quad*8 .. +8) of
    //      row (4bb+bcol, t). 4 cr-lanes share an address (HW broadcast). ----
    const size_t xrow = (size_t)(4 * bb + bcol) * NT;
    const __fp16* xhb = xh + xrow * NI + quad * 8;
    const float*  xfb = x  + xrow * NI + quad * 8;

    // register ring: f16 path depth 4 (loads issued 4 steps ahead);
    // f32 fallback depth 2. All indices static after unroll.
    f16x8 xf[4][4];
    f32x4 xr[2][8];
    if constexpr (XF16) {
        #pragma unroll
        for (int d = 0; d < 4; ++d)
            #pragma unroll
            for (int ks = 0; ks < 4; ++ks)
                xf[d][ks] = *(const f16x8*)(xhb + (size_t)d * NI + ks * 32);
    } else {
        #pragma unroll
        for (int d = 0; d < 2; ++d)
            #pragma unroll
            for (int ks = 0; ks < 4; ++ks) {
                xr[d][2*ks]   = *(const f32x4*)(xfb + (size_t)d * NI + ks * 32);
                xr[d][2*ks+1] = *(const f32x4*)(xfb + (size_t)d * NI + ks * 32 + 4);
            }
    }

    block_sync_lds();       // publish H2 zeros

    float c = 0.f;
    for (int k = 0; k < NT / 4; ++k) {
        #pragma unroll
        for (int tt = 0; tt < 4; ++tt) {
            const int t   = 4 * k + tt;
            const int cur = tt & 1;                 // == t&1
            // 1) h-frag reads: the latency shadow
            const __fp16* Hc = &H2[cur][bcol][quad * 8];
            f16x8 hb0 = *(const f16x8*)(Hc);
            f16x8 hb1 = *(const f16x8*)(Hc + 32);
            // 2) x B-frags from the register ring (no lgkm, no stall)
            f16x8 xb0, xb1, xb2, xb3;
            if constexpr (XF16) {
                xb0 = xf[tt][0]; xb1 = xf[tt][1];
                xb2 = xf[tt][2]; xb3 = xf[tt][3];
            } else {
                xb0 = pack8n((float4&)xr[tt & 1][0], (float4&)xr[tt & 1][1]);
                xb1 = pack8n((float4&)xr[tt & 1][2], (float4&)xr[tt & 1][3]);
                xb2 = pack8n((float4&)xr[tt & 1][4], (float4&)xr[tt & 1][5]);
                xb3 = pack8n((float4&)xr[tt & 1][6], (float4&)xr[tt & 1][7]);
            }
            // 3) 16 x-MFMAs (bias-seeded, same order as R9 producer ->
            //    bit-identical); issue inside the hb-read shadow. g (a2) first.
            f32x4 a0 = biasf[0], a1 = biasf[1], a2 = biasf[2], a3 = biasf[3];
            MF(a2, afrX[2][0], xb0); MF(a0, afrX[0][0], xb0);
            MF(a1, afrX[1][0], xb0); MF(a3, afrX[3][0], xb0);
            MF(a2, afrX[2][1], xb1); MF(a0, afrX[0][1], xb1);
            MF(a1, afrX[1][1], xb1); MF(a3, afrX[3][1], xb1);
            MF(a2, afrX[2][2], xb2); MF(a0, afrX[0][2], xb2);
            MF(a1, afrX[1][2], xb2); MF(a3, afrX[3][2], xb2);
            MF(a2, afrX[2][3], xb3); MF(a0, afrX[0][3], xb3);
            MF(a1, afrX[1][3], xb3); MF(a3, afrX[3][3], xb3);
            // 4) 8 h-MFMAs once hb lands; a2 finishes first
            MF(a2, afrH[2][0], hb0); MF(a0, afrH[0][0], hb0);
            MF(a1, afrH[1][0], hb0); MF(a3, afrH[3][0], hb0);
            MF(a2, afrH[2][1], hb1); MF(a0, afrH[0][1], hb1);
            MF(a1, afrH[1][1], hb1); MF(a3, afrH[3][1], hb1);
            // 5) reissue ring loads (vm pipe; lands >=2-4 steps later; the
            //    lgkm-only barrier never drains these)
            if constexpr (XF16) {
                if (k + 1 < NT / 4) {
                    const __fp16* p = xhb + (size_t)(t + 4) * NI;
                    xf[tt][0] = *(const f16x8*)(p);
                    xf[tt][1] = *(const f16x8*)(p + 32);
                    xf[tt][2] = *(const f16x8*)(p + 64);
                    xf[tt][3] = *(const f16x8*)(p + 96);
                }
            } else {
                if (t + 2 < NT) {
                    const float* p = xfb + (size_t)(t + 2) * NI;
                    #pragma unroll
                    for (int ks = 0; ks < 4; ++ks) {
                        xr[tt & 1][2*ks]   = *(const f32x4*)(p + ks * 32);
                        xr[tt & 1][2*ks+1] = *(const f32x4*)(p + ks * 32 + 4);
                    }
                }
            }
            // 6) activation: one unit (u=16w+4quad+cr, batch bcol)
            float Eg = fast_exp2(fminf(a2[cr], 60.f));
            float Ei = fast_exp2(-a0[cr]);
            float Ef = fast_exp2(-a1[cr]);
            float Eo = fast_exp2(-a3[cr]);
            float ig = (Eg - 1.f) * fast_rcp((1.f + Ei) * (1.f + Eg));
            float fv = fast_rcp(1.f + Ef);
            c = fmaf(fv, c, ig);
            float Ec = fast_exp2(fminf(TWOLOG2E * c, 60.f));
            float h  = (Ec - 1.f) * fast_rcp((1.f + Eo) * (1.f + Ec));
            H2[cur ^ 1][bcol][16 * w + 4 * quad + cr] = (__fp16)h;
            block_sync_lds();       // lgkm-only; vm prefetches stay in flight
        }
    }
    // final h in H2[0] (t=1023: cur=1, writes buf 0); last barrier done.

    if (tid < 4 * NC) {
        const int bl = tid / NC, cl = tid % NC;
        float acc = b_cls[cl];
        const float* wc = W_cls + cl * NH;
        #pragma unroll 8
        for (int kk = 0; kk < NH; ++kk)
            acc = fmaf(wc[kk], (float)H2[0][bl][kk], acc);
        out[(4 * bb + bl) * NC + cl] = acc;
    }
}

extern "C" void kernel_launch(void* const* d_in, const int* in_sizes, int n_in,
                              void* d_out, int out_size, void* d_ws, size_t ws_size,
                              hipStream_t stream) {
    const float* x     = (const float*)d_in[0];
    const float* W_ih  = (const float*)d_in[1];
    const float* W_hh  = (const float*)d_in[2];
    const float* b_ih  = (const float*)d_in[3];
    const float* b_hh  = (const float*)d_in[4];
    const float* W_cls = (const float*)d_in[5];
    const float* b_cls = (const float*)d_in[6];
    float* out = (float*)d_out;

    const size_t need = (size_t)NB * NT * NI * sizeof(__fp16);  // 64 MiB
    if (d_ws != nullptr && ws_size >= need) {
        __fp16* xh = (__fp16*)d_ws;
        cast_x<<<1024, 256, 0, stream>>>(x, xh);
        lstm_rec<1><<<NB / 4, 256, 0, stream>>>(x, xh, W_ih, W_hh, b_ih, b_hh,
                                                W_cls, b_cls, out);
    } else {
        lstm_rec<0><<<NB / 4, 256, 0, stream>>>(x, nullptr, W_ih, W_hh, b_ih,
                                                b_hh, W_cls, b_cls, out);
    }
}